// Round 2
// baseline (2137.156 us; speedup 1.0000x reference)
//
#include <hip/hip_runtime.h>
#include <hip/hip_bf16.h>
#include <cstdint>

// LSTM (relu activations), B=128 T=256 F=4 H=1024, gate order i,f,g,o.
// v3: 8 clusters x 16 rows; 32 WGs x 32 units per cluster (256 WGs total).
//  * cluster = bid & 7 -> one XCD per cluster under round-robin dispatch:
//    the 32x re-read of the 32KB h-tile is served by that XCD's L2.
//    Correctness does NOT depend on placement (sc1 write-through + fresh
//    addresses fall through to LLC), only speed.
//  * read amplification per step: 16MB -> 8MB grid-wide.
//  * 32 units/WG: bfrag doubles to 8kk x 8 tiles (256 VGPR), af halves (M=16).
//  * plain fp32 out stores issued AFTER flag publish (vmcnt(0) waits only on
//    the single sc1 bf16 ex store).
//  * init Ust staging padded to 130 shorts/row (kills the 1.73e7 bank
//    conflicts from the bfrag gather); zpart padded stride 68.

#define B_SZ   128
#define T_SZ   256
#define H_SZ   1024
#define G_SZ   4096   // 4*H
#define ULD    130    // init staging leading dim (shorts)
#define ZLD    68     // zpart row stride (words)

typedef __attribute__((ext_vector_type(8))) short short8;
typedef __attribute__((ext_vector_type(4))) float f32x4;
typedef __attribute__((ext_vector_type(2))) float f32x2;

__device__ __forceinline__ short f2bf(float f) {
    union { float f; unsigned u; } a; a.f = f;
    unsigned r = a.u + 0x7fffu + ((a.u >> 16) & 1u);   // RNE
    return (short)(r >> 16);
}

__device__ __forceinline__ float sigmoidf_(float x) {
    return 1.0f / (1.0f + __expf(-x));
}

// 8 fp32 -> short8 bf16 (round half-up via +0x8000, pack hi16 pairs with v_perm)
__device__ __forceinline__ short8 pack8(f32x4 a, f32x4 b) {
    union { f32x4 v; unsigned u[4]; } ua, ub; ua.v = a; ub.v = b;
    union { short8 s; unsigned d[4]; } r;
    r.d[0] = __builtin_amdgcn_perm(ua.u[1] + 0x8000u, ua.u[0] + 0x8000u, 0x07060302u);
    r.d[1] = __builtin_amdgcn_perm(ua.u[3] + 0x8000u, ua.u[2] + 0x8000u, 0x07060302u);
    r.d[2] = __builtin_amdgcn_perm(ub.u[1] + 0x8000u, ub.u[0] + 0x8000u, 0x07060302u);
    r.d[3] = __builtin_amdgcn_perm(ub.u[3] + 0x8000u, ub.u[2] + 0x8000u, 0x07060302u);
    return r.s;
}

template<int BF16EX>
__global__ __launch_bounds__(256, 1)
void lstm_persistent(const float* __restrict__ x, const float* __restrict__ W,
                     const float* __restrict__ U, const float* __restrict__ bias,
                     float* __restrict__ out, unsigned* __restrict__ flags,
                     short* __restrict__ ex)
{
    __shared__ __align__(16) char smem[69632];
    short* Ust = (short*)smem;            // init staging: [256 k][130] bf16 (66560B)
    float* zpA = (float*)smem;            // step partials buf 0 (34816B)
    float* zpB = (float*)(smem + 34816);  // buf 1

    const int tid  = threadIdx.x;
    const int bid  = blockIdx.x;
    const int cl   = bid & 7;     // cluster 0..7 -> rows cl*16..+16 (XCD-local intent)
    const int jbb  = bid >> 3;    // 0..31 -> units jbb*32..+32
    const int w    = tid >> 6;    // wave 0..3 -> K slice [w*256, w*256+256)
    const int lane = tid & 63;
    const int q    = lane >> 4;   // quad 0..3
    const int n    = lane & 15;

    // ---------- init: build persistent B fragments from U (fp32 -> bf16) ----------
    short8 bfrag[8][8];           // [kk (32-k chunk within wave slice)][tile = g*2+half]
    for (int kc = 0; kc < 4; ++kc) {
        const int kbase = kc * 256;
        for (int i = tid; i < 256 * 128; i += 256) {
            int k = i >> 7, col = i & 127;            // col = g*32 + rem
            int g = col >> 5, rem = col & 31;
            Ust[k * ULD + col] =
                f2bf(U[(size_t)(kbase + k) * G_SZ + g * 1024 + jbb * 32 + rem]);
        }
        __syncthreads();
        if (w == kc) {
            #pragma unroll
            for (int kk = 0; kk < 8; ++kk) {
                #pragma unroll
                for (int tile = 0; tile < 8; ++tile) {
                    short8 bb;
                    #pragma unroll
                    for (int jj = 0; jj < 8; ++jj)
                        bb[jj] = Ust[(kk * 32 + q * 8 + jj) * ULD + tile * 16 + n];
                    bfrag[kk][tile] = bb;
                }
            }
        }
        __syncthreads();
    }

    // ---------- per-thread epilogue constants ----------
    const int r_l   = tid >> 4;           // 0..15 row within cluster
    const int cp    = tid & 15;           // column pair -> units 2cp, 2cp+1
    const int row_g = cl * 16 + r_l;
    const int u0    = jbb * 32 + cp * 2;  // global unit (even)
    const int hf    = cp >> 3;            // tile half
    const int c0    = (cp * 2) & 15;      // within-tile col of unit 0
    const int qr    = r_l >> 2, vr = r_l & 3;
    float Wr[2][4][4], br[2][4];
    #pragma unroll
    for (int j = 0; j < 2; ++j)
        #pragma unroll
        for (int g = 0; g < 4; ++g) {
            br[j][g] = bias[g * 1024 + u0 + j];
            #pragma unroll
            for (int f = 0; f < 4; ++f)
                Wr[j][g][f] = W[(size_t)f * G_SZ + g * 1024 + u0 + j];
        }
    float cst[2] = {0.f, 0.f};

    const int arow = cl * 16 + n;         // A-frag row (per lane)
    const int krow = w * 256 + q * 8;
    // flags[cl*128 + jbb*4 + wave] = #steps produced by that wave
    const unsigned* pollp = flags + cl * 128 + w * 32 + (lane & 31);
    unsigned* pubp = flags + cl * 128 + jbb * 4 + w;

    // ---------- time loop ----------
    for (int t = 0; t < T_SZ; ++t) {
        f32x4 xv = *(const f32x4*)(x + ((size_t)row_g * T_SZ + t) * 4);

        // A fragments: h_{t-1}
        short8 af[8];
        if (t == 0) {
            short8 z = {};
            #pragma unroll
            for (int kk = 0; kk < 8; ++kk) af[kk] = z;
        } else {
            // wait for the 32 producer-waves (8 WGs x 4 waves) covering my K slice
            for (;;) {
                unsigned v = __hip_atomic_load(pollp, __ATOMIC_RELAXED,
                                               __HIP_MEMORY_SCOPE_AGENT);
                if (__all((int)(v >= (unsigned)t))) break;
                __builtin_amdgcn_s_sleep(2);
            }
            __atomic_signal_fence(__ATOMIC_ACQUIRE);  // compiler-only ordering

            if (BF16EX) {
                #pragma unroll
                for (int kk = 0; kk < 8; ++kk)
                    af[kk] = *(const short8*)(ex +
                        ((size_t)arow * T_SZ + (t - 1)) * H_SZ + krow + kk * 32);
            } else {
                #pragma unroll
                for (int kk = 0; kk < 8; ++kk) {
                    const float* p = out +
                        ((size_t)arow * T_SZ + (t - 1)) * H_SZ + krow + kk * 32;
                    f32x4 lo = *(const f32x4*)p;
                    f32x4 hi = *(const f32x4*)(p + 4);
                    af[kk] = pack8(lo, hi);
                }
            }
        }

        f32x4 acc[8];
        #pragma unroll
        for (int tl = 0; tl < 8; ++tl) acc[tl] = (f32x4){0.f, 0.f, 0.f, 0.f};

        #pragma unroll
        for (int kk = 0; kk < 8; ++kk)
            #pragma unroll
            for (int tl = 0; tl < 8; ++tl)
                acc[tl] = __builtin_amdgcn_mfma_f32_16x16x32_bf16(
                    af[kk], bfrag[kk][tl], acc[tl], 0, 0, 0);

        // K-split partials -> LDS, [ (w*8+tile)*4+q ][ZLD] rows, b128 writes
        float* zp = (t & 1) ? zpB : zpA;
        #pragma unroll
        for (int tl = 0; tl < 8; ++tl)
            *(f32x4*)&zp[(size_t)(((w * 8 + tl) * 4 + q) * ZLD) + n * 4] = acc[tl];
        __syncthreads();   // single barrier per step (dbuf'd)

        // ---------- epilogue ----------
        float hh[2];
        #pragma unroll
        for (int j = 0; j < 2; ++j) {
            float z[4];
            #pragma unroll
            for (int g = 0; g < 4; ++g) {
                float s = br[j][g];
                #pragma unroll
                for (int ww = 0; ww < 4; ++ww)
                    s += zp[(size_t)(((ww * 8 + g * 2 + hf) * 4 + qr) * ZLD) +
                            (c0 + j) * 4 + vr];
                s += xv[0] * Wr[j][g][0] + xv[1] * Wr[j][g][1] +
                     xv[2] * Wr[j][g][2] + xv[3] * Wr[j][g][3];
                z[g] = s;
            }
            float ig = sigmoidf_(z[0]), fg = sigmoidf_(z[1]);
            float gg = fmaxf(z[2], 0.f), og = sigmoidf_(z[3]);
            cst[j] = fg * cst[j] + ig * gg;
            hh[j] = og * fmaxf(cst[j], 0.f);
        }

        const size_t obase = ((size_t)row_g * T_SZ + t) * H_SZ + u0;
        if (BF16EX) {
            unsigned pw = (unsigned)(unsigned short)f2bf(hh[0]) |
                          ((unsigned)(unsigned short)f2bf(hh[1]) << 16);
            __hip_atomic_store((unsigned*)&ex[obase], pw, __ATOMIC_RELAXED,
                               __HIP_MEMORY_SCOPE_AGENT);
        } else {
            __hip_atomic_store((unsigned*)&out[obase], __float_as_uint(hh[0]),
                               __ATOMIC_RELAXED, __HIP_MEMORY_SCOPE_AGENT);
            __hip_atomic_store((unsigned*)&out[obase + 1], __float_as_uint(hh[1]),
                               __ATOMIC_RELAXED, __HIP_MEMORY_SCOPE_AGENT);
        }

        if (t != T_SZ - 1) {
            // publish: my exchange store acked at LLC -> flag = t+1
            asm volatile("s_waitcnt vmcnt(0)" ::: "memory");
            if (lane == 0)
                __hip_atomic_store(pubp, (unsigned)(t + 1),
                                   __ATOMIC_RELAXED, __HIP_MEMORY_SCOPE_AGENT);
        }

        if (BF16EX) {
            // fp32 output: plain writeback, off the critical ack path
            *(f32x2*)&out[obase] = (f32x2){hh[0], hh[1]};
        }

        if (t == T_SZ - 1) {
            float* hlast = out + (size_t)B_SZ * T_SZ * H_SZ;
            float* clast = hlast + (size_t)B_SZ * H_SZ;
            *(f32x2*)&hlast[(size_t)row_g * H_SZ + u0] = (f32x2){hh[0], hh[1]};
            *(f32x2*)&clast[(size_t)row_g * H_SZ + u0] = (f32x2){cst[0], cst[1]};
        }
    }
}

extern "C" void kernel_launch(void* const* d_in, const int* in_sizes, int n_in,
                              void* d_out, int out_size, void* d_ws, size_t ws_size,
                              hipStream_t stream) {
    const float* x    = (const float*)d_in[0];  // [128][256][4]
    const float* W    = (const float*)d_in[1];  // [4][4096]
    const float* U    = (const float*)d_in[2];  // [1024][4096]
    const float* bias = (const float*)d_in[3];  // [4096]
    float* out = (float*)d_out;                 // [128][256][1024] ++ h_last ++ c_last

    unsigned* flags = (unsigned*)d_ws;          // [8 cl][32 wg][4 wave] step flags
    short* ex = (short*)((char*)d_ws + 4096);   // bf16 h exchange [128][256][1024]

    // zero the flags (ws is poisoned 0xAA before every timed launch)
    hipMemsetAsync(d_ws, 0, 4096, stream);

    const size_t need = 4096 + (size_t)B_SZ * T_SZ * H_SZ * sizeof(short);
    if (ws_size >= need) {
        hipLaunchKernelGGL((lstm_persistent<1>), dim3(256), dim3(256), 0, stream,
                           x, W, U, bias, out, flags, ex);
    } else {
        hipLaunchKernelGGL((lstm_persistent<0>), dim3(256), dim3(256), 0, stream,
                           x, W, U, bias, out, flags, ex);
    }
}